// Round 5
// baseline (397.072 us; speedup 1.0000x reference)
//
#include <hip/hip_runtime.h>
#include <math.h>

#define B_ 128
#define D_ 128
#define Q_ 256
#define L_ 1024
#define BQ_ ((size_t)B_ * Q_)
#define BQL_ ((size_t)B_ * Q_ * L_)

typedef __attribute__((ext_vector_type(8))) short s16x8;
typedef __attribute__((ext_vector_type(4))) float f32x4;
typedef __attribute__((ext_vector_type(8))) _Float16 f16x8;

__device__ __forceinline__ unsigned short f2bf(float x) {
  unsigned u = __float_as_uint(x);
  u += 0x7FFF + ((u >> 16) & 1);  // round-to-nearest-even
  return (unsigned short)(u >> 16);
}
__device__ __forceinline__ float bf2f(unsigned short h) {
  return __uint_as_float(((unsigned)h) << 16);
}
__device__ __forceinline__ uint2 pack4bf(float4 v) {
  uint2 r;
  r.x = ((unsigned)f2bf(v.y) << 16) | (unsigned)f2bf(v.x);
  r.y = ((unsigned)f2bf(v.w) << 16) | (unsigned)f2bf(v.z);
  return r;
}
__device__ __forceinline__ void split8(const float* x, s16x8& hi, s16x8& lo) {
#pragma unroll
  for (int j = 0; j < 8; j++) {
    unsigned short h = f2bf(x[j]);
    hi[j] = (short)h;
    lo[j] = (short)f2bf(x[j] - bf2f(h));
  }
}

// ---------------------------------------------------------------------------
// P1 (fast path): split fp32 -> bf16 hi/lo AND transpose to k-fast layout:
//   Qs[b][q][0:128]=hi(k), [128:256]=lo(k);  Cs[b][l][0:128]|[128:256].
// After this, a K1 MFMA fragment (8 consecutive k for one row) is ONE
// global_load_dwordx4. LDS 128x132 fp32 tile transpose; reads 2-way (free).
// grid (10, B): x<2 -> query tiles, else ctx tiles.
// ---------------------------------------------------------------------------
__global__ __launch_bounds__(256) void p1_split(
    const float* __restrict__ query, const float* __restrict__ ctx,
    unsigned short* __restrict__ Qs, unsigned short* __restrict__ Cs) {
  __shared__ float T[128][132];
  const int b = blockIdx.y;
  const int xt = blockIdx.x;
  const float* src;
  unsigned short* dst;
  int C, c0;
  if (xt < 2) {
    src = query + (size_t)b * D_ * Q_;
    dst = Qs + (size_t)b * Q_ * 256;
    C = Q_;
    c0 = xt * 128;
  } else {
    src = ctx + (size_t)b * D_ * L_;
    dst = Cs + (size_t)b * L_ * 256;
    C = L_;
    c0 = (xt - 2) * 128;
  }
  const int t = threadIdx.x;
  const int col4 = (t & 31) * 4, kr = t >> 5;
#pragma unroll
  for (int i = 0; i < 16; i++) {
    const int k = kr + i * 8;
    *(float4*)&T[k][col4] = *(const float4*)(src + (size_t)k * C + c0 + col4);
  }
  __syncthreads();
  const int q = t >> 1, half = t & 1;
  unsigned short* drow = dst + (size_t)(c0 + q) * 256;
#pragma unroll
  for (int g = 0; g < 8; g++) {
    const int k0 = half * 64 + g * 8;
    float x[8];
#pragma unroll
    for (int j = 0; j < 8; j++) x[j] = T[k0 + j][q];
    uint4 vh, vl;
    unsigned hh[8], ll[8];
#pragma unroll
    for (int j = 0; j < 8; j++) {
      unsigned short h = f2bf(x[j]);
      hh[j] = h;
      ll[j] = f2bf(x[j] - bf2f(h));
    }
    vh.x = hh[0] | (hh[1] << 16);
    vh.y = hh[2] | (hh[3] << 16);
    vh.z = hh[4] | (hh[5] << 16);
    vh.w = hh[6] | (hh[7] << 16);
    vl.x = ll[0] | (ll[1] << 16);
    vl.y = ll[2] | (ll[3] << 16);
    vl.z = ll[4] | (ll[5] << 16);
    vl.w = ll[6] | (ll[7] << 16);
    *(uint4*)&drow[k0] = vh;
    *(uint4*)&drow[128 + k0] = vl;
  }
}

// ---------------------------------------------------------------------------
// K1 fast: attn_q = softmax_q(query^T ctx) via split-bf16 MFMA (hh+hl+lh),
// fragments loaded DIRECTLY from the k-fast split arrays (1 dwordx4 each,
// no LDS, no per-use split VALU). Block = 256q x 64l, 4 waves, BK=32.
// Epilogue: final softmax-1 (block covers all q) -> attn_q store
// (fp16 if F16 else fp32) + partial softmax-2 denominators pd[lt][b][q].
// grid (L/64, B)
// ---------------------------------------------------------------------------
template <bool F16>
__global__ __launch_bounds__(256) void k1_fast(
    const unsigned short* __restrict__ Qs, const unsigned short* __restrict__ Cs,
    void* __restrict__ attq, float* __restrict__ pd) {
  __shared__ float sm[4][64], ss[4][64], fm[64], fs[64];
  const int lt = blockIdx.x, b = blockIdx.y;
  const int l0 = lt * 64;
  const int tid = threadIdx.x;
  const int wq = tid >> 6;
  const int lane = tid & 63, quad = lane >> 4, l15 = lane & 15;

  const unsigned short* Qb = Qs + (size_t)b * Q_ * 256;
  const unsigned short* Cb = Cs + (size_t)b * L_ * 256;

  f32x4 acc[4][4];
#pragma unroll
  for (int mi = 0; mi < 4; mi++)
#pragma unroll
    for (int ni = 0; ni < 4; ni++) acc[mi][ni] = (f32x4){0.f, 0.f, 0.f, 0.f};

#pragma unroll 2
  for (int k0 = 0; k0 < D_; k0 += 32) {
    s16x8 ah[4], al[4], bh[4], bl[4];
#pragma unroll
    for (int mi = 0; mi < 4; mi++) {
      const unsigned short* p =
          Qb + (size_t)(wq * 64 + mi * 16 + l15) * 256 + k0 + quad * 8;
      ah[mi] = *(const s16x8*)p;
      al[mi] = *(const s16x8*)(p + 128);
    }
#pragma unroll
    for (int ni = 0; ni < 4; ni++) {
      const unsigned short* p =
          Cb + (size_t)(l0 + ni * 16 + l15) * 256 + k0 + quad * 8;
      bh[ni] = *(const s16x8*)p;
      bl[ni] = *(const s16x8*)(p + 128);
    }
#pragma unroll
    for (int mi = 0; mi < 4; mi++)
#pragma unroll
      for (int ni = 0; ni < 4; ni++) {
        acc[mi][ni] = __builtin_amdgcn_mfma_f32_16x16x32_bf16(
            ah[mi], bh[ni], acc[mi][ni], 0, 0, 0);
        acc[mi][ni] = __builtin_amdgcn_mfma_f32_16x16x32_bf16(
            ah[mi], bl[ni], acc[mi][ni], 0, 0, 0);
        acc[mi][ni] = __builtin_amdgcn_mfma_f32_16x16x32_bf16(
            al[mi], bh[ni], acc[mi][ni], 0, 0, 0);
      }
  }

  // first softmax over q (final: block covers all 256 q)
#pragma unroll
  for (int ni = 0; ni < 4; ni++) {
    float m = -1e30f;
#pragma unroll
    for (int mi = 0; mi < 4; mi++)
#pragma unroll
      for (int r = 0; r < 4; r++) m = fmaxf(m, acc[mi][ni][r]);
    m = fmaxf(m, __shfl_xor(m, 16));
    m = fmaxf(m, __shfl_xor(m, 32));
    float s = 0.f;
#pragma unroll
    for (int mi = 0; mi < 4; mi++)
#pragma unroll
      for (int r = 0; r < 4; r++) s += __expf(acc[mi][ni][r] - m);
    s += __shfl_xor(s, 16);
    s += __shfl_xor(s, 32);
    if (quad == 0) {
      sm[wq][ni * 16 + l15] = m;
      ss[wq][ni * 16 + l15] = s;
    }
  }
  __syncthreads();
  if (tid < 64) {
    float m0 = sm[0][tid], m1 = sm[1][tid], m2 = sm[2][tid], m3 = sm[3][tid];
    float M = fmaxf(fmaxf(m0, m1), fmaxf(m2, m3));
    float S = ss[0][tid] * __expf(m0 - M) + ss[1][tid] * __expf(m1 - M) +
              ss[2][tid] * __expf(m2 - M) + ss[3][tid] * __expf(m3 - M);
    fm[tid] = M;
    fs[tid] = 1.f / S;
  }
  __syncthreads();

  float fmv[4], fiv[4];
#pragma unroll
  for (int ni = 0; ni < 4; ni++) {
    fmv[ni] = fm[ni * 16 + l15];
    fiv[ni] = fs[ni * 16 + l15];
  }
  float dsum[4][4];
#pragma unroll
  for (int mi = 0; mi < 4; mi++)
#pragma unroll
    for (int r = 0; r < 4; r++) dsum[mi][r] = 0.f;

  const size_t rowbase = ((size_t)b * Q_ + wq * 64) * L_ + l0;
#pragma unroll
  for (int mi = 0; mi < 4; mi++)
#pragma unroll
    for (int r = 0; r < 4; r++) {
      const int q = mi * 16 + quad * 4 + r;
#pragma unroll
      for (int ni = 0; ni < 4; ni++) {
        float a = __expf(acc[mi][ni][r] - fmv[ni]) * fiv[ni];
        if (F16)
          ((_Float16*)attq)[rowbase + (size_t)q * L_ + ni * 16 + l15] =
              (_Float16)a;
        else
          ((float*)attq)[rowbase + (size_t)q * L_ + ni * 16 + l15] = a;
        dsum[mi][r] += __expf(4.f * a);
      }
    }
#pragma unroll
  for (int mi = 0; mi < 4; mi++)
#pragma unroll
    for (int r = 0; r < 4; r++) {
      float v = dsum[mi][r];
      v += __shfl_xor(v, 1);
      v += __shfl_xor(v, 2);
      v += __shfl_xor(v, 4);
      v += __shfl_xor(v, 8);
      if (l15 == 0)
        pd[(size_t)lt * BQ_ + b * Q_ + wq * 64 + mi * 16 + quad * 4 + r] = v;
    }
}

// ---------------------------------------------------------------------------
// K1 slow (fallback, R4): register-split fragments straight from fp32 global.
// ---------------------------------------------------------------------------
__global__ __launch_bounds__(256, 2) void k1_slow(
    const float* __restrict__ query, const float* __restrict__ ctx,
    float* __restrict__ attq, float* __restrict__ pd) {
  __shared__ float sm[4][64], ss[4][64], fm[64], fs[64];
  const int lt = blockIdx.x, b = blockIdx.y;
  const int l0 = lt * 64;
  const int tid = threadIdx.x;
  const int wq = tid >> 6;
  const int lane = tid & 63, quad = lane >> 4, l15 = lane & 15;

  const float* Qb = query + (size_t)b * D_ * Q_;
  const float* Cb = ctx + (size_t)b * D_ * L_ + l0;

  f32x4 acc[4][4];
#pragma unroll
  for (int mi = 0; mi < 4; mi++)
#pragma unroll
    for (int ni = 0; ni < 4; ni++) acc[mi][ni] = (f32x4){0.f, 0.f, 0.f, 0.f};

#pragma unroll 2
  for (int k0 = 0; k0 < D_; k0 += 32) {
    const int kq = k0 + quad * 8;
    s16x8 ah[4], al[4], bh[4], bl[4];
#pragma unroll
    for (int mi = 0; mi < 4; mi++) {
      const float* p = Qb + (size_t)kq * Q_ + wq * 64 + mi * 16 + l15;
      float x[8];
#pragma unroll
      for (int j = 0; j < 8; j++) x[j] = p[(size_t)j * Q_];
      split8(x, ah[mi], al[mi]);
    }
#pragma unroll
    for (int ni = 0; ni < 4; ni++) {
      const float* p = Cb + (size_t)kq * L_ + ni * 16 + l15;
      float x[8];
#pragma unroll
      for (int j = 0; j < 8; j++) x[j] = p[(size_t)j * L_];
      split8(x, bh[ni], bl[ni]);
    }
#pragma unroll
    for (int mi = 0; mi < 4; mi++)
#pragma unroll
      for (int ni = 0; ni < 4; ni++) {
        acc[mi][ni] = __builtin_amdgcn_mfma_f32_16x16x32_bf16(
            ah[mi], bh[ni], acc[mi][ni], 0, 0, 0);
        acc[mi][ni] = __builtin_amdgcn_mfma_f32_16x16x32_bf16(
            ah[mi], bl[ni], acc[mi][ni], 0, 0, 0);
        acc[mi][ni] = __builtin_amdgcn_mfma_f32_16x16x32_bf16(
            al[mi], bh[ni], acc[mi][ni], 0, 0, 0);
      }
  }

#pragma unroll
  for (int ni = 0; ni < 4; ni++) {
    float m = -1e30f;
#pragma unroll
    for (int mi = 0; mi < 4; mi++)
#pragma unroll
      for (int r = 0; r < 4; r++) m = fmaxf(m, acc[mi][ni][r]);
    m = fmaxf(m, __shfl_xor(m, 16));
    m = fmaxf(m, __shfl_xor(m, 32));
    float s = 0.f;
#pragma unroll
    for (int mi = 0; mi < 4; mi++)
#pragma unroll
      for (int r = 0; r < 4; r++) s += __expf(acc[mi][ni][r] - m);
    s += __shfl_xor(s, 16);
    s += __shfl_xor(s, 32);
    if (quad == 0) {
      sm[wq][ni * 16 + l15] = m;
      ss[wq][ni * 16 + l15] = s;
    }
  }
  __syncthreads();
  if (tid < 64) {
    float m0 = sm[0][tid], m1 = sm[1][tid], m2 = sm[2][tid], m3 = sm[3][tid];
    float M = fmaxf(fmaxf(m0, m1), fmaxf(m2, m3));
    float S = ss[0][tid] * __expf(m0 - M) + ss[1][tid] * __expf(m1 - M) +
              ss[2][tid] * __expf(m2 - M) + ss[3][tid] * __expf(m3 - M);
    fm[tid] = M;
    fs[tid] = 1.f / S;
  }
  __syncthreads();

  float fmv[4], fiv[4];
#pragma unroll
  for (int ni = 0; ni < 4; ni++) {
    fmv[ni] = fm[ni * 16 + l15];
    fiv[ni] = fs[ni * 16 + l15];
  }
  float* Ab = attq + ((size_t)b * Q_ + wq * 64) * L_ + l0;
  float dsum[4][4];
#pragma unroll
  for (int mi = 0; mi < 4; mi++)
#pragma unroll
    for (int r = 0; r < 4; r++) dsum[mi][r] = 0.f;
#pragma unroll
  for (int mi = 0; mi < 4; mi++)
#pragma unroll
    for (int r = 0; r < 4; r++) {
      const int q = mi * 16 + quad * 4 + r;
#pragma unroll
      for (int ni = 0; ni < 4; ni++) {
        float a = __expf(acc[mi][ni][r] - fmv[ni]) * fiv[ni];
        Ab[(size_t)q * L_ + ni * 16 + l15] = a;
        dsum[mi][r] += __expf(4.f * a);
      }
    }
#pragma unroll
  for (int mi = 0; mi < 4; mi++)
#pragma unroll
    for (int r = 0; r < 4; r++) {
      float v = dsum[mi][r];
      v += __shfl_xor(v, 1);
      v += __shfl_xor(v, 2);
      v += __shfl_xor(v, 4);
      v += __shfl_xor(v, 8);
      if (l15 == 0)
        pd[(size_t)lt * BQ_ + b * Q_ + wq * 64 + mi * 16 + quad * 4 + r] = v;
    }
}

// ---------------------------------------------------------------------------
// K2: invd[b][q] = 1 / sum of 16 partial denominators.
// ---------------------------------------------------------------------------
__global__ __launch_bounds__(256) void k2_invd(const float* __restrict__ pd,
                                               float* __restrict__ invd) {
  const int i = blockIdx.x * 256 + threadIdx.x;
  float s = 0.f;
#pragma unroll
  for (int t = 0; t < 16; t++) s += pd[(size_t)t * BQ_ + i];
  invd[i] = 1.f / s;
}

// ---------------------------------------------------------------------------
// K4: W = ctx @ attn_c^T via bf16 MFMA; second softmax fused into B-staging
// (attn_c = exp(4a)*invd), writing the fp32 attention map. F16: attn read as
// fp16 from ws, map written to its own region. F32: fp32 attn in map region,
// rewritten in place. m97-style LDS (BK=32, unpadded [row][32] shorts).
// Block 128d x 64q, grid (Q/64, B).
// ---------------------------------------------------------------------------
template <bool F16>
__global__ __launch_bounds__(256) void k4_weighted(
    const float* __restrict__ ctx, const void* __restrict__ attn,
    float* __restrict__ map, const float* __restrict__ invd,
    float* __restrict__ W) {
  __shared__ unsigned short As[128][32];
  __shared__ unsigned short Bs[64][32];
  const int b = blockIdx.y, q0 = blockIdx.x * 64;
  const int tid = threadIdx.x;
  const int w = tid >> 6, lane = tid & 63, quad = lane >> 4, l15 = lane & 15;
  const int wd = (w >> 1) * 64, wn = (w & 1) * 32;

  const float* Cb = ctx + (size_t)b * D_ * L_;
  const int lc = (tid & 7) * 4, rr = tid >> 3;

  // F16 B-staging mapping
  const int qv = tid >> 2, lc8 = (tid & 3) * 8;
  float idv = 0.f, id0 = 0.f, id1 = 0.f;
  if (F16) {
    idv = invd[b * Q_ + q0 + qv];
  } else {
    id0 = invd[b * Q_ + q0 + rr];
    id1 = invd[b * Q_ + q0 + rr + 32];
  }

  f32x4 acc[4][2];
#pragma unroll
  for (int mi = 0; mi < 4; mi++)
#pragma unroll
    for (int ni = 0; ni < 2; ni++) acc[mi][ni] = (f32x4){0.f, 0.f, 0.f, 0.f};

  for (int l0 = 0; l0 < L_; l0 += 32) {
    if (l0) __syncthreads();
#pragma unroll
    for (int h = 0; h < 4; h++) {  // A: 128d x 32l
      const int d = rr + h * 32;
      float4 cv = *(const float4*)(Cb + (size_t)d * L_ + l0 + lc);
      *(uint2*)&As[d][lc] = pack4bf(cv);
    }
    if (F16) {  // B: 64q x 32l from fp16 attn_q
      const _Float16* Arow =
          (const _Float16*)attn + ((size_t)b * Q_ + q0 + qv) * L_ + l0 + lc8;
      f16x8 av = *(const f16x8*)Arow;
      float t[8];
#pragma unroll
      for (int j = 0; j < 8; j++) t[j] = __expf(4.f * (float)av[j]) * idv;
      float* Mrow = map + ((size_t)b * Q_ + q0 + qv) * L_ + l0 + lc8;
      *(float4*)Mrow = make_float4(t[0], t[1], t[2], t[3]);
      *(float4*)(Mrow + 4) = make_float4(t[4], t[5], t[6], t[7]);
      uint4 pk;
      pk.x = (unsigned)f2bf(t[0]) | ((unsigned)f2bf(t[1]) << 16);
      pk.y = (unsigned)f2bf(t[2]) | ((unsigned)f2bf(t[3]) << 16);
      pk.z = (unsigned)f2bf(t[4]) | ((unsigned)f2bf(t[5]) << 16);
      pk.w = (unsigned)f2bf(t[6]) | ((unsigned)f2bf(t[7]) << 16);
      *(uint4*)&Bs[qv][lc8] = pk;
    } else {
#pragma unroll
      for (int h = 0; h < 2; h++) {
        const int q = rr + h * 32;
        float* p = map + ((size_t)b * Q_ + q0 + q) * L_ + l0 + lc;
        float4 a = *(const float4*)p;
        const float iv = h ? id1 : id0;
        float4 t;
        t.x = __expf(4.f * a.x) * iv;
        t.y = __expf(4.f * a.y) * iv;
        t.z = __expf(4.f * a.z) * iv;
        t.w = __expf(4.f * a.w) * iv;
        *(float4*)p = t;
        *(uint2*)&Bs[q][lc] = pack4bf(t);
      }
    }
    __syncthreads();

    s16x8 af[4], bq[2];
#pragma unroll
    for (int mi = 0; mi < 4; mi++)
      af[mi] = *(const s16x8*)&As[wd + mi * 16 + l15][quad * 8];
#pragma unroll
    for (int ni = 0; ni < 2; ni++)
      bq[ni] = *(const s16x8*)&Bs[wn + ni * 16 + l15][quad * 8];
#pragma unroll
    for (int mi = 0; mi < 4; mi++)
#pragma unroll
      for (int ni = 0; ni < 2; ni++)
        acc[mi][ni] = __builtin_amdgcn_mfma_f32_16x16x32_bf16(
            af[mi], bq[ni], acc[mi][ni], 0, 0, 0);
  }

  float* Wb = W + (size_t)b * D_ * Q_;
#pragma unroll
  for (int mi = 0; mi < 4; mi++)
#pragma unroll
    for (int ni = 0; ni < 2; ni++)
#pragma unroll
      for (int r = 0; r < 4; r++)
        Wb[(size_t)(wd + mi * 16 + quad * 4 + r) * Q_ + q0 + wn + ni * 16 +
           l15] = acc[mi][ni][r];
}

// ---------------------------------------------------------------------------
// Fast path (ws >= 69.4 MB): attn fp16 + pd + invd in d_ws; Qs (16.8 MB,
// exact fit) in the W region; Cs (67 MB) in the map region. Stream order
// makes every overlap safe: P1 writes Qs/Cs -> K1 reads them, writes attn16 ->
// K4 reads attn16/ctx, writes map (over Cs) and W (over Qs).
// Fallback: R4 structure (fp32 attn in map region, in-place rewrite).
// ---------------------------------------------------------------------------
extern "C" void kernel_launch(void* const* d_in, const int* in_sizes, int n_in,
                              void* d_out, int out_size, void* d_ws,
                              size_t ws_size, hipStream_t stream) {
  const float* query = (const float*)d_in[0];
  const float* ctx = (const float*)d_in[1];
  float* W = (float*)d_out;
  float* map = (float*)d_out + (size_t)B_ * D_ * Q_;

  const size_t need_fast = BQL_ * 2 + 17 * BQ_ * 4;
  if (ws_size >= need_fast && d_ws) {
    _Float16* attn16 = (_Float16*)d_ws;
    float* pd = (float*)((char*)d_ws + BQL_ * 2);
    float* invd = pd + 16 * BQ_;
    unsigned short* Qs = (unsigned short*)W;    // B*Q*256 shorts = 16.8 MB
    unsigned short* Cs = (unsigned short*)map;  // B*L*256 shorts = 67 MB

    p1_split<<<dim3(10, B_), 256, 0, stream>>>(query, ctx, Qs, Cs);
    k1_fast<true><<<dim3(L_ / 64, B_), 256, 0, stream>>>(Qs, Cs, attn16, pd);
    k2_invd<<<dim3(BQ_ / 256), 256, 0, stream>>>(pd, invd);
    k4_weighted<true><<<dim3(Q_ / 64, B_), 256, 0, stream>>>(ctx, attn16, map,
                                                             invd, W);
  } else {
    const size_t need_pd = 17 * BQ_ * 4;
    float* pd = (ws_size >= need_pd && d_ws) ? (float*)d_ws : W;
    float* invd = pd + 16 * BQ_;
    k1_slow<<<dim3(L_ / 64, B_), 256, 0, stream>>>(query, ctx, map, pd);
    k2_invd<<<dim3(BQ_ / 256), 256, 0, stream>>>(pd, invd);
    k4_weighted<false><<<dim3(Q_ / 64, B_), 256, 0, stream>>>(ctx, map, map,
                                                              invd, W);
  }
}

// Round 6
// 349.391 us; speedup vs baseline: 1.1365x; 1.1365x over previous
//
#include <hip/hip_runtime.h>
#include <math.h>

#define B_ 128
#define D_ 128
#define Q_ 256
#define L_ 1024
#define BQ_ ((size_t)B_ * Q_)

typedef __attribute__((ext_vector_type(8))) short s16x8;
typedef __attribute__((ext_vector_type(4))) float f32x4;

__device__ __forceinline__ unsigned short f2bf(float x) {
  unsigned u = __float_as_uint(x);
  u += 0x7FFF + ((u >> 16) & 1);  // round-to-nearest-even
  return (unsigned short)(u >> 16);
}
__device__ __forceinline__ float bf2f(unsigned short h) {
  return __uint_as_float(((unsigned)h) << 16);
}
__device__ __forceinline__ uint2 pack4bf(float4 v) {
  uint2 r;
  r.x = ((unsigned)f2bf(v.y) << 16) | (unsigned)f2bf(v.x);
  r.y = ((unsigned)f2bf(v.w) << 16) | (unsigned)f2bf(v.z);
  return r;
}
__device__ __forceinline__ void split8(const float* x, s16x8& hi, s16x8& lo) {
#pragma unroll
  for (int j = 0; j < 8; j++) {
    unsigned short h = f2bf(x[j]);
    hi[j] = (short)h;
    lo[j] = (short)f2bf(x[j] - bf2f(h));
  }
}

// ---------------------------------------------------------------------------
// P1q: split QUERY ONLY fp32 -> k-fast hi/lo bf16: Qs[b][q][0:128]=hi(k),
// [128:256]=lo(k). Qs = 16.8 MB = the W output region EXACTLY (dead until
// K4's epilogue). After this a K1 A-fragment is ONE dwordx4 (L2-hot).
// LDS 128x132 transpose: float4 loads, column reads 2-way aliased (free).
// grid (2, B): 128-column halves of the 256-q slice.
// ---------------------------------------------------------------------------
__global__ __launch_bounds__(256) void p1q_split(
    const float* __restrict__ query, unsigned short* __restrict__ Qs) {
  __shared__ float T[128][132];
  const int b = blockIdx.y, c0 = blockIdx.x * 128;
  const float* src = query + (size_t)b * D_ * Q_;
  const int t = threadIdx.x;
  const int col4 = (t & 31) * 4, kr = t >> 5;
#pragma unroll
  for (int i = 0; i < 16; i++) {
    const int k = kr + i * 8;
    *(float4*)&T[k][col4] = *(const float4*)(src + (size_t)k * Q_ + c0 + col4);
  }
  __syncthreads();
  const int q = t >> 1, half = t & 1;
  unsigned short* drow = Qs + (size_t)(b * Q_ + c0 + q) * 256;
#pragma unroll
  for (int g = 0; g < 8; g++) {
    const int k0 = half * 64 + g * 8;
    unsigned hh[8], ll[8];
#pragma unroll
    for (int j = 0; j < 8; j++) {
      float x = T[k0 + j][q];
      unsigned short h = f2bf(x);
      hh[j] = h;
      ll[j] = f2bf(x - bf2f(h));
    }
    uint4 vh, vl;
    vh.x = hh[0] | (hh[1] << 16);
    vh.y = hh[2] | (hh[3] << 16);
    vh.z = hh[4] | (hh[5] << 16);
    vh.w = hh[6] | (hh[7] << 16);
    vl.x = ll[0] | (ll[1] << 16);
    vl.y = ll[2] | (ll[3] << 16);
    vl.z = ll[4] | (ll[5] << 16);
    vl.w = ll[6] | (ll[7] << 16);
    *(uint4*)&drow[k0] = vh;
    *(uint4*)&drow[128 + k0] = vl;
  }
}

// ---------------------------------------------------------------------------
// K1: attn_q = softmax_q(query^T ctx), split-bf16 MFMA (hh+hl+lh).
// A-fragments: direct dwordx4 from k-fast Qs (no VALU). B-fragments: scalar
// fp32 loads + in-register split (R4 path) with 2-chunk register prefetch so
// HBM loads for chunk c+1 overlap chunk c's MFMAs. Block 256q x 64l, 4 waves
// (one 64q strip each), BK=32. Epilogue: final softmax-1 -> attn_q fp32 into
// the map region + partial softmax-2 denominators pd[lt][b][q].
// grid (L/64, B)
// ---------------------------------------------------------------------------
__global__ __launch_bounds__(256, 2) void k1_mid(
    const unsigned short* __restrict__ Qs, const float* __restrict__ ctx,
    float* __restrict__ attq, float* __restrict__ pd) {
  __shared__ float sm[4][64], ss[4][64], fm[64], fs[64];
  const int lt = blockIdx.x, b = blockIdx.y;
  const int l0 = lt * 64;
  const int tid = threadIdx.x;
  const int wq = tid >> 6;
  const int lane = tid & 63, quad = lane >> 4, l15 = lane & 15;

  const unsigned short* Qb = Qs + (size_t)b * Q_ * 256;
  const float* Cb = ctx + (size_t)b * D_ * L_ + l0;

  f32x4 acc[4][4];
#pragma unroll
  for (int mi = 0; mi < 4; mi++)
#pragma unroll
    for (int ni = 0; ni < 4; ni++) acc[mi][ni] = (f32x4){0.f, 0.f, 0.f, 0.f};

  // B prefetch buffers: xb[parity][ni][j]
  float xb[2][4][8];
#pragma unroll
  for (int ni = 0; ni < 4; ni++) {
    const float* p = Cb + (size_t)(quad * 8) * L_ + ni * 16 + l15;
#pragma unroll
    for (int j = 0; j < 8; j++) xb[0][ni][j] = p[(size_t)j * L_];
  }

#pragma unroll
  for (int c = 0; c < 4; c++) {
    const int k0 = c * 32;
    const int cur = c & 1, nxt = cur ^ 1;
    // A fragments: single dwordx4 each from Qs
    s16x8 ah[4], al[4];
#pragma unroll
    for (int mi = 0; mi < 4; mi++) {
      const unsigned short* p =
          Qb + (size_t)(wq * 64 + mi * 16 + l15) * 256 + k0 + quad * 8;
      ah[mi] = *(const s16x8*)p;
      al[mi] = *(const s16x8*)(p + 128);
    }
    // prefetch next B chunk (HBM) before consuming current
    if (c < 3) {
#pragma unroll
      for (int ni = 0; ni < 4; ni++) {
        const float* p = Cb + (size_t)(k0 + 32 + quad * 8) * L_ + ni * 16 + l15;
#pragma unroll
        for (int j = 0; j < 8; j++) xb[nxt][ni][j] = p[(size_t)j * L_];
      }
    }
    // split current B
    s16x8 bh[4], bl[4];
#pragma unroll
    for (int ni = 0; ni < 4; ni++) split8(xb[cur][ni], bh[ni], bl[ni]);
#pragma unroll
    for (int mi = 0; mi < 4; mi++)
#pragma unroll
      for (int ni = 0; ni < 4; ni++) {
        acc[mi][ni] = __builtin_amdgcn_mfma_f32_16x16x32_bf16(
            ah[mi], bh[ni], acc[mi][ni], 0, 0, 0);
        acc[mi][ni] = __builtin_amdgcn_mfma_f32_16x16x32_bf16(
            ah[mi], bl[ni], acc[mi][ni], 0, 0, 0);
        acc[mi][ni] = __builtin_amdgcn_mfma_f32_16x16x32_bf16(
            al[mi], bh[ni], acc[mi][ni], 0, 0, 0);
      }
  }

  // first softmax over q (final: block covers all 256 q)
#pragma unroll
  for (int ni = 0; ni < 4; ni++) {
    float m = -1e30f;
#pragma unroll
    for (int mi = 0; mi < 4; mi++)
#pragma unroll
      for (int r = 0; r < 4; r++) m = fmaxf(m, acc[mi][ni][r]);
    m = fmaxf(m, __shfl_xor(m, 16));
    m = fmaxf(m, __shfl_xor(m, 32));
    float s = 0.f;
#pragma unroll
    for (int mi = 0; mi < 4; mi++)
#pragma unroll
      for (int r = 0; r < 4; r++) s += __expf(acc[mi][ni][r] - m);
    s += __shfl_xor(s, 16);
    s += __shfl_xor(s, 32);
    if (quad == 0) {
      sm[wq][ni * 16 + l15] = m;
      ss[wq][ni * 16 + l15] = s;
    }
  }
  __syncthreads();
  if (tid < 64) {
    float m0 = sm[0][tid], m1 = sm[1][tid], m2 = sm[2][tid], m3 = sm[3][tid];
    float M = fmaxf(fmaxf(m0, m1), fmaxf(m2, m3));
    float S = ss[0][tid] * __expf(m0 - M) + ss[1][tid] * __expf(m1 - M) +
              ss[2][tid] * __expf(m2 - M) + ss[3][tid] * __expf(m3 - M);
    fm[tid] = M;
    fs[tid] = 1.f / S;
  }
  __syncthreads();

  float fmv[4], fiv[4];
#pragma unroll
  for (int ni = 0; ni < 4; ni++) {
    fmv[ni] = fm[ni * 16 + l15];
    fiv[ni] = fs[ni * 16 + l15];
  }
  float* Ab = attq + ((size_t)b * Q_ + wq * 64) * L_ + l0;
  float dsum[4][4];
#pragma unroll
  for (int mi = 0; mi < 4; mi++)
#pragma unroll
    for (int r = 0; r < 4; r++) dsum[mi][r] = 0.f;
#pragma unroll
  for (int mi = 0; mi < 4; mi++)
#pragma unroll
    for (int r = 0; r < 4; r++) {
      const int q = mi * 16 + quad * 4 + r;
#pragma unroll
      for (int ni = 0; ni < 4; ni++) {
        float a = __expf(acc[mi][ni][r] - fmv[ni]) * fiv[ni];
        Ab[(size_t)q * L_ + ni * 16 + l15] = a;
        dsum[mi][r] += __expf(4.f * a);
      }
    }
#pragma unroll
  for (int mi = 0; mi < 4; mi++)
#pragma unroll
    for (int r = 0; r < 4; r++) {
      float v = dsum[mi][r];
      v += __shfl_xor(v, 1);
      v += __shfl_xor(v, 2);
      v += __shfl_xor(v, 4);
      v += __shfl_xor(v, 8);
      if (l15 == 0)
        pd[(size_t)lt * BQ_ + b * Q_ + wq * 64 + mi * 16 + quad * 4 + r] = v;
    }
}

// ---------------------------------------------------------------------------
// K2: invd[b][q] = 1 / sum of 16 partial denominators. ~2 MB.
// ---------------------------------------------------------------------------
__global__ __launch_bounds__(256) void k2_invd(const float* __restrict__ pd,
                                               float* __restrict__ invd) {
  const int i = blockIdx.x * 256 + threadIdx.x;
  float s = 0.f;
#pragma unroll
  for (int t = 0; t < 16; t++) s += pd[(size_t)t * BQ_ + i];
  invd[i] = 1.f / s;
}

// ---------------------------------------------------------------------------
// K4: W = ctx @ attn_c^T, bf16 MFMA; second softmax fused into B-staging
// (attn_c = exp(4a)*invd), attention map rewritten IN PLACE (fp32, same
// address, element-wise -> cross-block safe: each block owns its q-rows).
// Register prefetch: staging float4s for chunk l0+32 issued right after the
// post-staging barrier, in flight during chunk-l0 MFMAs. m97-style LDS
// (BK=32, unpadded [row][32] shorts). Block 128d x 64q, grid (Q/64, B).
// ---------------------------------------------------------------------------
__global__ __launch_bounds__(256) void k4_weighted(
    const float* __restrict__ ctx, float* __restrict__ map,
    const float* __restrict__ invd, float* __restrict__ W) {
  __shared__ unsigned short As[128][32];
  __shared__ unsigned short Bs[64][32];
  const int b = blockIdx.y, q0 = blockIdx.x * 64;
  const int tid = threadIdx.x;
  const int w = tid >> 6, lane = tid & 63, quad = lane >> 4, l15 = lane & 15;
  const int wd = (w >> 1) * 64, wn = (w & 1) * 32;

  const float* Cb = ctx + (size_t)b * D_ * L_;
  const int lc = (tid & 7) * 4, rr = tid >> 3;
  const float id0 = invd[b * Q_ + q0 + rr];
  const float id1 = invd[b * Q_ + q0 + rr + 32];

  f32x4 acc[4][2];
#pragma unroll
  for (int mi = 0; mi < 4; mi++)
#pragma unroll
    for (int ni = 0; ni < 2; ni++) acc[mi][ni] = (f32x4){0.f, 0.f, 0.f, 0.f};

  float4 cva[4], ava[2];
#pragma unroll
  for (int h = 0; h < 4; h++)
    cva[h] = *(const float4*)(Cb + (size_t)(rr + h * 32) * L_ + lc);
#pragma unroll
  for (int h = 0; h < 2; h++)
    ava[h] =
        *(const float4*)(map + ((size_t)b * Q_ + q0 + rr + h * 32) * L_ + lc);

  for (int l0 = 0; l0 < L_; l0 += 32) {
    if (l0) __syncthreads();
#pragma unroll
    for (int h = 0; h < 4; h++) *(uint2*)&As[rr + h * 32][lc] = pack4bf(cva[h]);
#pragma unroll
    for (int h = 0; h < 2; h++) {
      const int q = rr + h * 32;
      const float iv = h ? id1 : id0;
      float4 t;
      t.x = __expf(4.f * ava[h].x) * iv;
      t.y = __expf(4.f * ava[h].y) * iv;
      t.z = __expf(4.f * ava[h].z) * iv;
      t.w = __expf(4.f * ava[h].w) * iv;
      *(float4*)(map + ((size_t)b * Q_ + q0 + q) * L_ + l0 + lc) = t;
      *(uint2*)&Bs[q][lc] = pack4bf(t);
    }
    __syncthreads();

    if (l0 + 32 < L_) {  // prefetch next chunk under the MFMAs
#pragma unroll
      for (int h = 0; h < 4; h++)
        cva[h] =
            *(const float4*)(Cb + (size_t)(rr + h * 32) * L_ + l0 + 32 + lc);
#pragma unroll
      for (int h = 0; h < 2; h++)
        ava[h] = *(const float4*)(map + ((size_t)b * Q_ + q0 + rr + h * 32) *
                                            L_ + l0 + 32 + lc);
    }

    s16x8 af[4], bq[2];
#pragma unroll
    for (int mi = 0; mi < 4; mi++)
      af[mi] = *(const s16x8*)&As[wd + mi * 16 + l15][quad * 8];
#pragma unroll
    for (int ni = 0; ni < 2; ni++)
      bq[ni] = *(const s16x8*)&Bs[wn + ni * 16 + l15][quad * 8];
#pragma unroll
    for (int mi = 0; mi < 4; mi++)
#pragma unroll
      for (int ni = 0; ni < 2; ni++)
        acc[mi][ni] = __builtin_amdgcn_mfma_f32_16x16x32_bf16(
            af[mi], bq[ni], acc[mi][ni], 0, 0, 0);
  }

  float* Wb = W + (size_t)b * D_ * Q_;
#pragma unroll
  for (int mi = 0; mi < 4; mi++)
#pragma unroll
    for (int ni = 0; ni < 2; ni++)
#pragma unroll
      for (int r = 0; r < 4; r++)
        Wb[(size_t)(wd + mi * 16 + quad * 4 + r) * Q_ + q0 + wn + ni * 16 +
           l15] = acc[mi][ni][r];
}

// ---------------------------------------------------------------------------
// d_out: [W 16.8 MB | map 134 MB]. P1q writes Qs into the W region (exact
// fit); K1 reads Qs + ctx, writes attn_q fp32 into the map region + pd
// (2.2 MB, d_ws — small dirty footprint; R5 showed dirtying ~70 MB of ws
// triggers a ~103 us harness poison fill per iteration). K4 rewrites the map
// in place as attn_c and overwrites the W region (Qs dead) with the result.
// ---------------------------------------------------------------------------
extern "C" void kernel_launch(void* const* d_in, const int* in_sizes, int n_in,
                              void* d_out, int out_size, void* d_ws,
                              size_t ws_size, hipStream_t stream) {
  const float* query = (const float*)d_in[0];
  const float* ctx = (const float*)d_in[1];
  float* W = (float*)d_out;
  float* map = (float*)d_out + (size_t)B_ * D_ * Q_;
  unsigned short* Qs = (unsigned short*)W;

  const size_t need_pd = 17 * BQ_ * sizeof(float);
  float* pd = (ws_size >= need_pd && d_ws) ? (float*)d_ws : map;  // ws in practice
  float* invd = pd + 16 * BQ_;

  p1q_split<<<dim3(2, B_), 256, 0, stream>>>(query, Qs);
  k1_mid<<<dim3(L_ / 64, B_), 256, 0, stream>>>(Qs, ctx, map, pd);
  k2_invd<<<dim3(BQ_ / 256), 256, 0, stream>>>(pd, invd);
  k4_weighted<<<dim3(Q_ / 64, B_), 256, 0, stream>>>(ctx, map, invd, W);
}